// Round 1
// baseline (219.734 us; speedup 1.0000x reference)
//
#include <hip/hip_runtime.h>
#include <hip/hip_bf16.h>
#include <stdint.h>

// B=32, S=4096, ENC=512, DEC=512
// out = softmax_s( sum_d tanh( enc @ W_e^T + dh @ W_h^T + b ) * v )

typedef __attribute__((ext_vector_type(8))) short short8;
typedef __attribute__((ext_vector_type(4))) float f32x4;

static __device__ __forceinline__ unsigned short f2bf(float f) {
    union { float f; uint32_t u; } x{f};
    uint32_t u = x.u;
    u += 0x7fffu + ((u >> 16) & 1u);   // RNE
    return (unsigned short)(u >> 16);
}

// ---------------------------------------------------------------------------
// Kernel 1 (96 blocks x 512):
//   blocks 0..63 : convert W_e (= W_attn[:,512:]) to bf16, K-tiled [kt][n][64]
//                  with per-row XOR swizzle (byte ^= (n&7)<<4 on 16B groups)
//                  so the main kernel can global_load_lds it linearly.
//   blocks 64..95: proj1[b][e] = sum_d dh[b,d]*W_attn[e,d] + b_attn[e]
// ---------------------------------------------------------------------------
__global__ __launch_bounds__(512) void prep_kernel(
    const float* __restrict__ dh, const float* __restrict__ W_attn,
    const float* __restrict__ b_attn, unsigned short* __restrict__ wsB,
    float* __restrict__ wsP1) {
    __shared__ float dhs[512];
    const int tid = threadIdx.x;
    if (blockIdx.x < 64) {
        int idx = blockIdx.x * 512 + tid;      // 0..32767
        int c8 = idx & 7;                       // 16B group in row
        int n  = (idx >> 3) & 511;              // W_e output row (d)
        int kt = idx >> 12;                     // K tile 0..7
        const float* src = W_attn + (size_t)n * 1024 + 512 + kt * 64 + c8 * 8;
        float4 f0 = *(const float4*)(src);
        float4 f1 = *(const float4*)(src + 4);
        short8 p;
        p[0] = (short)f2bf(f0.x); p[1] = (short)f2bf(f0.y);
        p[2] = (short)f2bf(f0.z); p[3] = (short)f2bf(f0.w);
        p[4] = (short)f2bf(f1.x); p[5] = (short)f2bf(f1.y);
        p[6] = (short)f2bf(f1.z); p[7] = (short)f2bf(f1.w);
        int row = kt * 512 + n;
        int byteInRow = (c8 * 16) ^ ((n & 7) << 4);
        *(short8*)((char*)wsB + (size_t)row * 128 + byteInRow) = p;
    } else {
        int b = blockIdx.x - 64;
        dhs[tid] = dh[b * 512 + tid];
        __syncthreads();
        const float* wrow = W_attn + (size_t)tid * 1024;  // W_h row e=tid
        float acc = 0.f;
        #pragma unroll 8
        for (int d = 0; d < 512; d += 4) {
            float4 w = *(const float4*)(wrow + d);
            acc += dhs[d] * w.x + dhs[d + 1] * w.y + dhs[d + 2] * w.z + dhs[d + 3] * w.w;
        }
        wsP1[b * 512 + tid] = acc + b_attn[tid];
    }
}

// ---------------------------------------------------------------------------
// Kernel 2: fused GEMM (64 rows x 512 cols per block, K=512) + tanh + v-dot.
// 8 waves; wave w owns cols [64w, 64w+64) as 4x4 frags of 16x16x32 bf16 MFMA.
// Writes scores (pre-softmax) to out[m].
// ---------------------------------------------------------------------------
__global__ __launch_bounds__(512, 2) void fused_kernel(
    const float* __restrict__ enc, const unsigned short* __restrict__ wsB,
    const float* __restrict__ wsP1, const float* __restrict__ vvec,
    float* __restrict__ out) {
    __shared__ char lds[73728];                         // A 8KB | B 64KB
    unsigned short* A_lds = (unsigned short*)lds;       // [64][64] bf16, swizzled
    char*           B_lds = lds + 8192;                 // [512][64] bf16, swizzled

    const int tid  = threadIdx.x;
    const int wave = tid >> 6;
    const int lane = tid & 63;
    const int llo  = lane & 15, lhi = lane >> 4;
    const int m0   = blockIdx.x * 64;
    const int b    = m0 >> 12;                          // 4096 rows per batch, 64|4096

    // A staging: thread -> (row ar, 16B group ac8)
    const int ar = tid >> 3, ac8 = tid & 7;
    const float* aptr = enc + (size_t)(m0 + ar) * 512 + ac8 * 8;
    char* aDst = (char*)A_lds + ar * 128 + ((ac8 * 16) ^ ((ar & 7) << 4));

    f32x4 acc[4][4] = {};

    for (int kt = 0; kt < 8; ++kt) {
        // --- stage A: 8 f32 -> 8 bf16 -> one ds_write_b128 (swizzled dest)
        float4 f0 = *(const float4*)(aptr + kt * 64);
        float4 f1 = *(const float4*)(aptr + kt * 64 + 4);
        short8 ap;
        ap[0] = (short)f2bf(f0.x); ap[1] = (short)f2bf(f0.y);
        ap[2] = (short)f2bf(f0.z); ap[3] = (short)f2bf(f0.w);
        ap[4] = (short)f2bf(f1.x); ap[5] = (short)f2bf(f1.y);
        ap[6] = (short)f2bf(f1.z); ap[7] = (short)f2bf(f1.w);
        *(short8*)aDst = ap;

        // --- stage B: 64KB linear copy of pre-swizzled W_e K-tile
        const char* bsrc = (const char*)wsB + (size_t)kt * 65536;
        #pragma unroll
        for (int i = 0; i < 8; ++i) {
            int off = (i * 8 + wave) * 1024;
            __builtin_amdgcn_global_load_lds(
                (const uint32_t __attribute__((address_space(1)))*)(bsrc + off + lane * 16),
                (uint32_t __attribute__((address_space(3)))*)(B_lds + off),
                16, 0, 0);
        }
        __syncthreads();   // drains vmcnt+lgkmcnt

        #pragma unroll
        for (int kk = 0; kk < 2; ++kk) {
            const int gbyte = kk * 64 + lhi * 16;
            short8 af[4], bfr[4];
            #pragma unroll
            for (int mi = 0; mi < 4; ++mi) {
                int row = mi * 16 + llo;
                af[mi] = *(const short8*)((const char*)A_lds + row * 128 +
                                          (gbyte ^ ((row & 7) << 4)));
            }
            #pragma unroll
            for (int ni = 0; ni < 4; ++ni) {
                int n = wave * 64 + ni * 16 + llo;
                bfr[ni] = *(const short8*)(B_lds + n * 128 +
                                           (gbyte ^ ((n & 7) << 4)));
            }
            #pragma unroll
            for (int mi = 0; mi < 4; ++mi)
                #pragma unroll
                for (int ni = 0; ni < 4; ++ni)
                    acc[mi][ni] = __builtin_amdgcn_mfma_f32_16x16x32_bf16(
                        af[mi], bfr[ni], acc[mi][ni], 0, 0, 0);
        }
        __syncthreads();
    }

    // --- epilogue: tanh(acc + proj1[b,d]) * v[d], reduce over d ---
    float p1v[4], vv[4];
    #pragma unroll
    for (int ni = 0; ni < 4; ++ni) {
        int d = wave * 64 + ni * 16 + llo;
        p1v[ni] = wsP1[b * 512 + d];
        vv[ni]  = vvec[d];
    }
    float part[16];
    #pragma unroll
    for (int mi = 0; mi < 4; ++mi)
        #pragma unroll
        for (int r = 0; r < 4; ++r) {
            float s = 0.f;
            #pragma unroll
            for (int ni = 0; ni < 4; ++ni) {
                float pj = acc[mi][ni][r] + p1v[ni];
                s += tanhf(pj) * vv[ni];
            }
            part[mi * 4 + r] = s;
        }
    // reduce across the 16-lane column group (lane bits 0..3)
    #pragma unroll
    for (int off = 1; off < 16; off <<= 1)
        #pragma unroll
        for (int i = 0; i < 16; ++i)
            part[i] += __shfl_xor(part[i], off, 64);

    float* red = (float*)lds;   // [8 waves][64 rows]; K-loop done, safe to reuse
    if (llo == 0) {
        #pragma unroll
        for (int mi = 0; mi < 4; ++mi)
            #pragma unroll
            for (int r = 0; r < 4; ++r)
                red[wave * 64 + mi * 16 + lhi * 4 + r] = part[mi * 4 + r];
    }
    __syncthreads();
    if (tid < 64) {
        float s = 0.f;
        #pragma unroll
        for (int w = 0; w < 8; ++w) s += red[w * 64 + tid];
        out[m0 + tid] = s;
    }
}

// ---------------------------------------------------------------------------
// Kernel 3: row softmax over S=4096, in place on out. 32 blocks x 256.
// ---------------------------------------------------------------------------
__global__ __launch_bounds__(256) void softmax_kernel(float* __restrict__ out) {
    __shared__ float wred[8];
    const int b = blockIdx.x, tid = threadIdx.x;
    float* row = out + (size_t)b * 4096;
    float vals[16];
    float lmax = -1e30f;
    #pragma unroll
    for (int i = 0; i < 16; ++i) {
        vals[i] = row[i * 256 + tid];
        lmax = fmaxf(lmax, vals[i]);
    }
    #pragma unroll
    for (int off = 32; off >= 1; off >>= 1)
        lmax = fmaxf(lmax, __shfl_xor(lmax, off, 64));
    if ((tid & 63) == 0) wred[tid >> 6] = lmax;
    __syncthreads();
    float gmax = fmaxf(fmaxf(wred[0], wred[1]), fmaxf(wred[2], wred[3]));
    float lsum = 0.f;
    #pragma unroll
    for (int i = 0; i < 16; ++i) {
        vals[i] = expf(vals[i] - gmax);
        lsum += vals[i];
    }
    #pragma unroll
    for (int off = 32; off >= 1; off >>= 1)
        lsum += __shfl_xor(lsum, off, 64);
    if ((tid & 63) == 0) wred[4 + (tid >> 6)] = lsum;
    __syncthreads();
    float inv = 1.f / (wred[4] + wred[5] + wred[6] + wred[7]);
    #pragma unroll
    for (int i = 0; i < 16; ++i)
        row[i * 256 + tid] = vals[i] * inv;
}

extern "C" void kernel_launch(void* const* d_in, const int* in_sizes, int n_in,
                              void* d_out, int out_size, void* d_ws, size_t ws_size,
                              hipStream_t stream) {
    const float* dh   = (const float*)d_in[0];   // (32, 512)
    const float* enc  = (const float*)d_in[1];   // (32, 4096, 512)
    const float* Wat  = (const float*)d_in[2];   // (512, 1024)
    const float* batt = (const float*)d_in[3];   // (512,)
    const float* vvec = (const float*)d_in[4];   // (512,)
    float* out = (float*)d_out;                  // (32, 4096)

    unsigned short* wsB = (unsigned short*)d_ws;               // 512 KB bf16 W_e
    float* wsP1 = (float*)((char*)d_ws + 512 * 512 * 2);       // 64 KB proj1

    hipLaunchKernelGGL(prep_kernel, dim3(96), dim3(512), 0, stream,
                       dh, Wat, batt, wsB, wsP1);
    hipLaunchKernelGGL(fused_kernel, dim3(2048), dim3(512), 0, stream,
                       enc, wsB, wsP1, vvec, out);
    hipLaunchKernelGGL(softmax_kernel, dim3(32), dim3(256), 0, stream, out);
}

// Round 2
// 162.346 us; speedup vs baseline: 1.3535x; 1.3535x over previous
//
#include <hip/hip_runtime.h>
#include <hip/hip_bf16.h>
#include <stdint.h>

// B=32, S=4096, ENC=512, DEC=512
// out = softmax_s( sum_d tanh( enc @ W_e^T + dh @ W_h^T + b ) * v )

typedef __attribute__((ext_vector_type(8))) short short8;
typedef __attribute__((ext_vector_type(4))) float f32x4;

static __device__ __forceinline__ unsigned short f2bf(float f) {
    union { float f; uint32_t u; } x{f};
    uint32_t u = x.u;
    u += 0x7fffu + ((u >> 16) & 1u);   // RNE
    return (unsigned short)(u >> 16);
}

static __device__ __forceinline__ float tanh_fast(float x) {
    // tanh(x) = 1 - 2/(exp(2x)+1); exp overflow->inf->+1, underflow->0->-1 (both correct)
    return 1.0f - 2.0f / (__expf(2.0f * x) + 1.0f);
}

// ---------------------------------------------------------------------------
// Kernel 1 (96 blocks x 512):
//   blocks 0..63 : W_e (= W_attn[:,512:]) -> bf16, K-tiled [kt][n(512)][64],
//                  rows of 128B with XOR swizzle (16B-group ^= (n&7)) so the
//                  main kernel stages it linearly via global_load_lds.
//   blocks 64..95: proj1[b][e] = sum_d dh[b,d]*W_attn[e,d] + b_attn[e]
// ---------------------------------------------------------------------------
__global__ __launch_bounds__(512) void prep_kernel(
    const float* __restrict__ dh, const float* __restrict__ W_attn,
    const float* __restrict__ b_attn, unsigned short* __restrict__ wsB,
    float* __restrict__ wsP1) {
    __shared__ float dhs[512];
    const int tid = threadIdx.x;
    if (blockIdx.x < 64) {
        int idx = blockIdx.x * 512 + tid;      // 0..32767
        int c8 = idx & 7;                       // 16B group in row
        int n  = (idx >> 3) & 511;              // W_e row (output dim d)
        int kt = idx >> 12;                     // K tile 0..7
        const float* src = W_attn + (size_t)n * 1024 + 512 + kt * 64 + c8 * 8;
        float4 f0 = *(const float4*)(src);
        float4 f1 = *(const float4*)(src + 4);
        short8 p;
        p[0] = (short)f2bf(f0.x); p[1] = (short)f2bf(f0.y);
        p[2] = (short)f2bf(f0.z); p[3] = (short)f2bf(f0.w);
        p[4] = (short)f2bf(f1.x); p[5] = (short)f2bf(f1.y);
        p[6] = (short)f2bf(f1.z); p[7] = (short)f2bf(f1.w);
        int row = kt * 512 + n;
        int byteInRow = (c8 * 16) ^ ((n & 7) << 4);
        *(short8*)((char*)wsB + (size_t)row * 128 + byteInRow) = p;
    } else {
        int b = blockIdx.x - 64;
        dhs[tid] = dh[b * 512 + tid];
        __syncthreads();
        const float* wrow = W_attn + (size_t)tid * 1024;  // W_h row e=tid
        float acc = 0.f;
        #pragma unroll 8
        for (int d = 0; d < 512; d += 4) {
            float4 w = *(const float4*)(wrow + d);
            acc += dhs[d] * w.x + dhs[d + 1] * w.y + dhs[d + 2] * w.z + dhs[d + 3] * w.w;
        }
        wsP1[b * 512 + tid] = acc + b_attn[tid];
    }
}

// ---------------------------------------------------------------------------
// Kernel 2: fused GEMM (128 rows x 512 cols per block, K=512) + tanh + v-dot.
// 8 waves as 2(M)x4(N); wave tile 64x128 = 4x8 frags of 16x16x32 bf16 MFMA.
// Double-buffered LDS (A 2x16KB + B 2x64KB = 160KB), T3-minimum pipeline:
// issue next tile's loads before this tile's MFMAs, one barrier per tile.
// ---------------------------------------------------------------------------
__global__ __launch_bounds__(512, 2) void fused_kernel(
    const float* __restrict__ enc, const unsigned short* __restrict__ wsB,
    const float* __restrict__ wsP1, const float* __restrict__ vvec,
    float* __restrict__ out) {
    __shared__ char lds[163840];
    char* const Abuf[2] = { lds, lds + 16384 };          // [128][64] bf16 swz
    char* const Bbuf[2] = { lds + 32768, lds + 98304 };  // [512][64] bf16 swz

    const int tid  = threadIdx.x;
    const int wave = tid >> 6;
    const int lane = tid & 63;
    const int llo  = lane & 15, lhi = lane >> 4;
    const int wr   = wave >> 2, wc = wave & 3;           // wave -> (rowblk, colblk)
    const int m0   = blockIdx.x * 128;
    const int b    = m0 >> 12;                           // 128 | 4096

    // A staging map: thread -> (row ar, 16-elem K chunk ac)
    const int ar = tid >> 2, ac = tid & 3;
    const float* aptr = enc + (size_t)(m0 + ar) * 512 + ac * 16;
    const int aoff0 = ar * 128 + (((ac * 32)     ) ^ ((ar & 7) << 4));
    const int aoff1 = ar * 128 + (((ac * 32) + 16) ^ ((ar & 7) << 4));

    f32x4 acc[4][8] = {};
    float4 fa0, fa1, fa2, fa3;

    #define STAGE_A_LOAD(kt)                               \
        do { const float* p_ = aptr + (kt) * 64;           \
             fa0 = *(const float4*)(p_);                   \
             fa1 = *(const float4*)(p_ + 4);               \
             fa2 = *(const float4*)(p_ + 8);               \
             fa3 = *(const float4*)(p_ + 12); } while (0)

    #define STAGE_A_WRITE(Adst)                                          \
        do { short8 p0_, p1_;                                            \
             p0_[0]=(short)f2bf(fa0.x); p0_[1]=(short)f2bf(fa0.y);       \
             p0_[2]=(short)f2bf(fa0.z); p0_[3]=(short)f2bf(fa0.w);       \
             p0_[4]=(short)f2bf(fa1.x); p0_[5]=(short)f2bf(fa1.y);       \
             p0_[6]=(short)f2bf(fa1.z); p0_[7]=(short)f2bf(fa1.w);       \
             p1_[0]=(short)f2bf(fa2.x); p1_[1]=(short)f2bf(fa2.y);       \
             p1_[2]=(short)f2bf(fa2.z); p1_[3]=(short)f2bf(fa2.w);       \
             p1_[4]=(short)f2bf(fa3.x); p1_[5]=(short)f2bf(fa3.y);       \
             p1_[6]=(short)f2bf(fa3.z); p1_[7]=(short)f2bf(fa3.w);       \
             *(short8*)((Adst) + aoff0) = p0_;                           \
             *(short8*)((Adst) + aoff1) = p1_; } while (0)

    #define STAGE_B(kt, Bdst)                                                      \
        do { const char* bsrc_ = (const char*)wsB + (size_t)(kt) * 65536;          \
             _Pragma("unroll")                                                     \
             for (int i_ = 0; i_ < 8; ++i_) {                                      \
                 int off_ = (i_ * 8 + wave) * 1024;                                \
                 __builtin_amdgcn_global_load_lds(                                 \
                     (const uint32_t __attribute__((address_space(1)))*)(bsrc_ + off_ + lane * 16), \
                     (uint32_t __attribute__((address_space(3)))*)((Bdst) + off_), \
                     16, 0, 0);                                                    \
             } } while (0)

    #define COMPUTE(Asrc, Bsrc)                                                    \
        do { _Pragma("unroll")                                                     \
             for (int kk = 0; kk < 2; ++kk) {                                      \
                 const int gbyte = kk * 64 + lhi * 16;                             \
                 short8 af[4], bfr[8];                                             \
                 _Pragma("unroll")                                                 \
                 for (int mi = 0; mi < 4; ++mi) {                                  \
                     int row = wr * 64 + mi * 16 + llo;                            \
                     af[mi] = *(const short8*)((Asrc) + row * 128 +                \
                                               (gbyte ^ ((row & 7) << 4)));        \
                 }                                                                 \
                 _Pragma("unroll")                                                 \
                 for (int ni = 0; ni < 8; ++ni) {                                  \
                     int n = wc * 128 + ni * 16 + llo;                             \
                     bfr[ni] = *(const short8*)((Bsrc) + n * 128 +                 \
                                                (gbyte ^ ((n & 7) << 4)));         \
                 }                                                                 \
                 _Pragma("unroll")                                                 \
                 for (int mi = 0; mi < 4; ++mi)                                    \
                     _Pragma("unroll")                                             \
                     for (int ni = 0; ni < 8; ++ni)                                \
                         acc[mi][ni] = __builtin_amdgcn_mfma_f32_16x16x32_bf16(    \
                             af[mi], bfr[ni], acc[mi][ni], 0, 0, 0);               \
             } } while (0)

    // prologue: stage tile 0 into buffer 0
    STAGE_A_LOAD(0);
    STAGE_B(0, Bbuf[0]);
    STAGE_A_WRITE(Abuf[0]);
    __syncthreads();

    #pragma unroll
    for (int kt = 0; kt < 8; ++kt) {
        const int cur = kt & 1, nxt = cur ^ 1;
        if (kt < 7) {
            STAGE_A_LOAD(kt + 1);        // f32 -> regs (HBM latency hides under MFMA)
            STAGE_B(kt + 1, Bbuf[nxt]);  // global_load_lds, in flight across MFMAs
        }
        COMPUTE(Abuf[cur], Bbuf[cur]);
        if (kt < 7) STAGE_A_WRITE(Abuf[nxt]);
        __syncthreads();                 // vmcnt(0) lgkmcnt(0) + barrier, once per tile
    }

    // --- epilogue: tanh(acc + proj1[b,d]) * v[d], reduce over d ---
    float p1v[8], vv[8];
    #pragma unroll
    for (int ni = 0; ni < 8; ++ni) {
        int d = wc * 128 + ni * 16 + llo;
        p1v[ni] = wsP1[b * 512 + d];
        vv[ni]  = vvec[d];
    }
    float part[16];
    #pragma unroll
    for (int mi = 0; mi < 4; ++mi)
        #pragma unroll
        for (int r = 0; r < 4; ++r) {
            float s = 0.f;
            #pragma unroll
            for (int ni = 0; ni < 8; ++ni)
                s += tanh_fast(acc[mi][ni][r] + p1v[ni]) * vv[ni];
            part[mi * 4 + r] = s;
        }
    // reduce across the 16-lane column group (lane bits 0..3)
    #pragma unroll
    for (int off = 1; off < 16; off <<= 1)
        #pragma unroll
        for (int i = 0; i < 16; ++i)
            part[i] += __shfl_xor(part[i], off, 64);

    float* red = (float*)lds;   // [4 wc][128 rows]; K-loop done, safe to reuse
    if (llo == 0) {
        #pragma unroll
        for (int mi = 0; mi < 4; ++mi)
            #pragma unroll
            for (int r = 0; r < 4; ++r)
                red[wc * 128 + wr * 64 + mi * 16 + lhi * 4 + r] = part[mi * 4 + r];
    }
    __syncthreads();
    if (tid < 128) {
        float s = red[tid] + red[128 + tid] + red[256 + tid] + red[384 + tid];
        out[m0 + tid] = s;
    }
}

// ---------------------------------------------------------------------------
// Kernel 3: row softmax over S=4096, in place on out. 32 blocks x 256.
// ---------------------------------------------------------------------------
__global__ __launch_bounds__(256) void softmax_kernel(float* __restrict__ out) {
    __shared__ float wred[8];
    const int b = blockIdx.x, tid = threadIdx.x;
    float* row = out + (size_t)b * 4096;
    float vals[16];
    float lmax = -1e30f;
    #pragma unroll
    for (int i = 0; i < 16; ++i) {
        vals[i] = row[i * 256 + tid];
        lmax = fmaxf(lmax, vals[i]);
    }
    #pragma unroll
    for (int off = 32; off >= 1; off >>= 1)
        lmax = fmaxf(lmax, __shfl_xor(lmax, off, 64));
    if ((tid & 63) == 0) wred[tid >> 6] = lmax;
    __syncthreads();
    float gmax = fmaxf(fmaxf(wred[0], wred[1]), fmaxf(wred[2], wred[3]));
    float lsum = 0.f;
    #pragma unroll
    for (int i = 0; i < 16; ++i) {
        vals[i] = expf(vals[i] - gmax);
        lsum += vals[i];
    }
    #pragma unroll
    for (int off = 32; off >= 1; off >>= 1)
        lsum += __shfl_xor(lsum, off, 64);
    if ((tid & 63) == 0) wred[4 + (tid >> 6)] = lsum;
    __syncthreads();
    float inv = 1.f / (wred[4] + wred[5] + wred[6] + wred[7]);
    #pragma unroll
    for (int i = 0; i < 16; ++i)
        row[i * 256 + tid] = vals[i] * inv;
}

extern "C" void kernel_launch(void* const* d_in, const int* in_sizes, int n_in,
                              void* d_out, int out_size, void* d_ws, size_t ws_size,
                              hipStream_t stream) {
    const float* dh   = (const float*)d_in[0];   // (32, 512)
    const float* enc  = (const float*)d_in[1];   // (32, 4096, 512)
    const float* Wat  = (const float*)d_in[2];   // (512, 1024)
    const float* batt = (const float*)d_in[3];   // (512,)
    const float* vvec = (const float*)d_in[4];   // (512,)
    float* out = (float*)d_out;                  // (32, 4096)

    unsigned short* wsB = (unsigned short*)d_ws;               // 512 KB bf16 W_e
    float* wsP1 = (float*)((char*)d_ws + 512 * 512 * 2);       // 64 KB proj1

    hipLaunchKernelGGL(prep_kernel, dim3(96), dim3(512), 0, stream,
                       dh, Wat, batt, wsB, wsP1);
    hipLaunchKernelGGL(fused_kernel, dim3(1024), dim3(512), 0, stream,
                       enc, wsB, wsP1, vvec, out);
    hipLaunchKernelGGL(softmax_kernel, dim3(32), dim3(256), 0, stream, out);
}

// Round 3
// 145.274 us; speedup vs baseline: 1.5126x; 1.1175x over previous
//
#include <hip/hip_runtime.h>
#include <hip/hip_bf16.h>
#include <stdint.h>

// B=32, S=4096, ENC=512, DEC=512
// out = softmax_s( sum_d tanh( enc @ W_e^T + dh @ W_h^T + b ) * v )

typedef __attribute__((ext_vector_type(8))) short short8;
typedef __attribute__((ext_vector_type(4))) float f32x4;

static __device__ __forceinline__ unsigned short f2bf(float f) {
    union { float f; uint32_t u; } x{f};
    uint32_t u = x.u;
    u += 0x7fffu + ((u >> 16) & 1u);   // RNE
    return (unsigned short)(u >> 16);
}

static __device__ __forceinline__ float tanh_fast(float x) {
    // tanh(x) = 1 - 2/(exp(2x)+1); overflow->+1, underflow->-1 (both correct)
    return 1.0f - 2.0f / (__expf(2.0f * x) + 1.0f);
}

// ---------------------------------------------------------------------------
// Kernel 1 (96 blocks x 512):
//   blocks 0..63 : W_e (= W_attn[:,512:]) -> bf16, K-tiled [kt][n(512)][64],
//                  128B rows, 16B-group XOR swizzle (^ (n&7)<<4) so the main
//                  kernel stages linearly via global_load_lds.
//   blocks 64..95: proj1[b][e] = sum_d dh[b,d]*W_attn[e,d] + b_attn[e]
// ---------------------------------------------------------------------------
__global__ __launch_bounds__(512) void prep_kernel(
    const float* __restrict__ dh, const float* __restrict__ W_attn,
    const float* __restrict__ b_attn, unsigned short* __restrict__ wsB,
    float* __restrict__ wsP1) {
    __shared__ float dhs[512];
    const int tid = threadIdx.x;
    if (blockIdx.x < 64) {
        int idx = blockIdx.x * 512 + tid;      // 0..32767
        int c8 = idx & 7;                       // 16B group in row
        int n  = (idx >> 3) & 511;              // W_e row (output dim d)
        int kt = idx >> 12;                     // K tile 0..7
        const float* src = W_attn + (size_t)n * 1024 + 512 + kt * 64 + c8 * 8;
        float4 f0 = *(const float4*)(src);
        float4 f1 = *(const float4*)(src + 4);
        short8 p;
        p[0] = (short)f2bf(f0.x); p[1] = (short)f2bf(f0.y);
        p[2] = (short)f2bf(f0.z); p[3] = (short)f2bf(f0.w);
        p[4] = (short)f2bf(f1.x); p[5] = (short)f2bf(f1.y);
        p[6] = (short)f2bf(f1.z); p[7] = (short)f2bf(f1.w);
        int row = kt * 512 + n;
        int byteInRow = (c8 * 16) ^ ((n & 7) << 4);
        *(short8*)((char*)wsB + (size_t)row * 128 + byteInRow) = p;
    } else {
        int b = blockIdx.x - 64;
        dhs[tid] = dh[b * 512 + tid];
        __syncthreads();
        const float* wrow = W_attn + (size_t)tid * 1024;  // W_h row e=tid
        float acc = 0.f;
        #pragma unroll 8
        for (int d = 0; d < 512; d += 4) {
            float4 w = *(const float4*)(wrow + d);
            acc += dhs[d] * w.x + dhs[d + 1] * w.y + dhs[d + 2] * w.z + dhs[d + 3] * w.w;
        }
        wsP1[b * 512 + tid] = acc + b_attn[tid];
    }
}

// ---------------------------------------------------------------------------
// Kernel 2: fused GEMM (64 rows x 256 cols per block, K=512) + tanh + v-dot.
// 256 thr = 4 waves (1M x 4N); wave tile 64x64 = 4x4 frags of 16x16x32 bf16.
// Single-buffered LDS 40KB (A 8KB + B 32KB) -> 3 blocks/CU: m97-style 2-barrier
// loop, latency hidden by co-resident blocks (m114 implicit overlap).
// cb=0 writes partial scores to out, cb=1 to wsS1; softmax adds them.
// ---------------------------------------------------------------------------
__global__ __launch_bounds__(256, 3) void fused_kernel(
    const float* __restrict__ enc, const unsigned short* __restrict__ wsB,
    const float* __restrict__ wsP1, const float* __restrict__ vvec,
    float* __restrict__ out, float* __restrict__ wsS1) {
    __shared__ char lds[40960];
    char* const A_lds = lds;            // [64][128B] bf16 swz
    char* const B_lds = lds + 8192;     // [256][128B] bf16 swz

    const int tid  = threadIdx.x;
    const int wc   = tid >> 6;                    // wave = N-block 0..3
    const int lane = tid & 63;
    const int llo  = lane & 15, lhi = lane >> 4;

    // XCD-chunked swizzle; 4096 % 8 == 0 so simple form is bijective.
    // Consecutive logical blocks (rb,cb=0/1) land 8 apart in dispatch order
    // -> same XCD -> shared enc tile is L2-hot.
    const int bid = blockIdx.x;
    const int lb  = (bid & 7) * 512 + (bid >> 3);
    const int rb  = lb >> 1, cb = lb & 1;
    const int m0  = rb * 64;
    const int b   = m0 >> 12;                     // batch (64 | 4096)

    // A staging map: thread -> (row ar, 16-f32 K chunk ac)
    const int ar = tid >> 2, ac = tid & 3;
    const float* aptr = enc + (size_t)(m0 + ar) * 512 + ac * 16;
    const int aoff0 = ar * 128 + (((ac * 32)     ) ^ ((ar & 7) << 4));
    const int aoff1 = ar * 128 + (((ac * 32) + 16) ^ ((ar & 7) << 4));
    const char* bbase = (const char*)wsB + cb * 32768;

    f32x4 acc[4][4] = {};
    float4 fa0, fa1, fa2, fa3;

    #define A_LOAD(kt)                                 \
        do { const float* p_ = aptr + (kt) * 64;       \
             fa0 = *(const float4*)(p_);               \
             fa1 = *(const float4*)(p_ + 4);           \
             fa2 = *(const float4*)(p_ + 8);           \
             fa3 = *(const float4*)(p_ + 12); } while (0)

    #define A_WRITE()                                                    \
        do { short8 p0_, p1_;                                            \
             p0_[0]=(short)f2bf(fa0.x); p0_[1]=(short)f2bf(fa0.y);       \
             p0_[2]=(short)f2bf(fa0.z); p0_[3]=(short)f2bf(fa0.w);       \
             p0_[4]=(short)f2bf(fa1.x); p0_[5]=(short)f2bf(fa1.y);       \
             p0_[6]=(short)f2bf(fa1.z); p0_[7]=(short)f2bf(fa1.w);       \
             p1_[0]=(short)f2bf(fa2.x); p1_[1]=(short)f2bf(fa2.y);       \
             p1_[2]=(short)f2bf(fa2.z); p1_[3]=(short)f2bf(fa2.w);       \
             p1_[4]=(short)f2bf(fa3.x); p1_[5]=(short)f2bf(fa3.y);       \
             p1_[6]=(short)f2bf(fa3.z); p1_[7]=(short)f2bf(fa3.w);       \
             *(short8*)(A_lds + aoff0) = p0_;                            \
             *(short8*)(A_lds + aoff1) = p1_; } while (0)

    #define B_GLDS(kt)                                                             \
        do { const char* bsrc_ = bbase + (size_t)(kt) * 65536;                     \
             _Pragma("unroll")                                                     \
             for (int i_ = 0; i_ < 8; ++i_) {                                      \
                 int off_ = i_ * 4096 + wc * 1024;                                 \
                 __builtin_amdgcn_global_load_lds(                                 \
                     (const uint32_t __attribute__((address_space(1)))*)(bsrc_ + off_ + lane * 16), \
                     (uint32_t __attribute__((address_space(3)))*)(B_lds + off_),  \
                     16, 0, 0);                                                    \
             } } while (0)

    #define COMPUTE()                                                              \
        do { _Pragma("unroll")                                                     \
             for (int kk = 0; kk < 2; ++kk) {                                      \
                 const int gbyte = kk * 64 + lhi * 16;                             \
                 short8 af[4], bfr[4];                                             \
                 _Pragma("unroll")                                                 \
                 for (int mi = 0; mi < 4; ++mi) {                                  \
                     int row = mi * 16 + llo;                                      \
                     af[mi] = *(const short8*)(A_lds + row * 128 +                 \
                                               (gbyte ^ ((row & 7) << 4)));        \
                 }                                                                 \
                 _Pragma("unroll")                                                 \
                 for (int ni = 0; ni < 4; ++ni) {                                  \
                     int n = wc * 64 + ni * 16 + llo;                              \
                     bfr[ni] = *(const short8*)(B_lds + n * 128 +                  \
                                                (gbyte ^ ((n & 7) << 4)));         \
                 }                                                                 \
                 _Pragma("unroll")                                                 \
                 for (int mi = 0; mi < 4; ++mi)                                    \
                     _Pragma("unroll")                                             \
                     for (int ni = 0; ni < 4; ++ni)                                \
                         acc[mi][ni] = __builtin_amdgcn_mfma_f32_16x16x32_bf16(    \
                             af[mi], bfr[ni], acc[mi][ni], 0, 0, 0);               \
             } } while (0)

    // prologue: stage tile 0
    A_LOAD(0);
    A_WRITE();
    B_GLDS(0);
    __syncthreads();

    #pragma unroll
    for (int kt = 0; kt < 8; ++kt) {
        if (kt < 7) A_LOAD(kt + 1);      // global->reg, hides under MFMAs
        COMPUTE();
        __syncthreads();                 // done reading tile kt
        if (kt < 7) {
            A_WRITE();
            B_GLDS(kt + 1);
            __syncthreads();             // tile kt+1 ready (drain, covered by
        }                                // the other 2 resident blocks)
    }

    // --- epilogue: tanh(acc + proj1[b,d]) * v[d], partial-reduce over d ---
    float p1v[4], vv[4];
    #pragma unroll
    for (int ni = 0; ni < 4; ++ni) {
        int d = cb * 256 + wc * 64 + ni * 16 + llo;
        p1v[ni] = wsP1[b * 512 + d];
        vv[ni]  = vvec[d];
    }
    float part[16];
    #pragma unroll
    for (int mi = 0; mi < 4; ++mi)
        #pragma unroll
        for (int r = 0; r < 4; ++r) {
            float s = 0.f;
            #pragma unroll
            for (int ni = 0; ni < 4; ++ni)
                s += tanh_fast(acc[mi][ni][r] + p1v[ni]) * vv[ni];
            part[mi * 4 + r] = s;
        }
    // reduce across the 16-lane column group (lane bits 0..3)
    #pragma unroll
    for (int off = 1; off < 16; off <<= 1)
        #pragma unroll
        for (int i = 0; i < 16; ++i)
            part[i] += __shfl_xor(part[i], off, 64);

    float* red = (float*)lds;   // [4 wc][64 rows]; K-loop done, safe to reuse
    if (llo == 0) {
        #pragma unroll
        for (int mi = 0; mi < 4; ++mi)
            #pragma unroll
            for (int r = 0; r < 4; ++r)
                red[wc * 64 + mi * 16 + lhi * 4 + r] = part[mi * 4 + r];
    }
    __syncthreads();
    if (tid < 64) {
        float s = red[tid] + red[64 + tid] + red[128 + tid] + red[192 + tid];
        (cb ? wsS1 : out)[m0 + tid] = s;
    }
}

// ---------------------------------------------------------------------------
// Kernel 3: add the two column-half partials, row softmax over S=4096,
// write to out. 32 blocks x 256.
// ---------------------------------------------------------------------------
__global__ __launch_bounds__(256) void softmax_kernel(
    float* __restrict__ out, const float* __restrict__ wsS1) {
    __shared__ float wred[8];
    const int b = blockIdx.x, tid = threadIdx.x;
    float* row = out + (size_t)b * 4096;
    const float* row1 = wsS1 + (size_t)b * 4096;
    float vals[16];
    float lmax = -1e30f;
    #pragma unroll
    for (int i = 0; i < 16; ++i) {
        vals[i] = row[i * 256 + tid] + row1[i * 256 + tid];
        lmax = fmaxf(lmax, vals[i]);
    }
    #pragma unroll
    for (int off = 32; off >= 1; off >>= 1)
        lmax = fmaxf(lmax, __shfl_xor(lmax, off, 64));
    if ((tid & 63) == 0) wred[tid >> 6] = lmax;
    __syncthreads();
    float gmax = fmaxf(fmaxf(wred[0], wred[1]), fmaxf(wred[2], wred[3]));
    float lsum = 0.f;
    #pragma unroll
    for (int i = 0; i < 16; ++i) {
        vals[i] = expf(vals[i] - gmax);
        lsum += vals[i];
    }
    #pragma unroll
    for (int off = 32; off >= 1; off >>= 1)
        lsum += __shfl_xor(lsum, off, 64);
    if ((tid & 63) == 0) wred[4 + (tid >> 6)] = lsum;
    __syncthreads();
    float inv = 1.f / (wred[4] + wred[5] + wred[6] + wred[7]);
    #pragma unroll
    for (int i = 0; i < 16; ++i)
        row[i * 256 + tid] = vals[i] * inv;
}

extern "C" void kernel_launch(void* const* d_in, const int* in_sizes, int n_in,
                              void* d_out, int out_size, void* d_ws, size_t ws_size,
                              hipStream_t stream) {
    const float* dh   = (const float*)d_in[0];   // (32, 512)
    const float* enc  = (const float*)d_in[1];   // (32, 4096, 512)
    const float* Wat  = (const float*)d_in[2];   // (512, 1024)
    const float* batt = (const float*)d_in[3];   // (512,)
    const float* vvec = (const float*)d_in[4];   // (512,)
    float* out = (float*)d_out;                  // (32, 4096)

    unsigned short* wsB = (unsigned short*)d_ws;               // 512 KB bf16 W_e
    float* wsP1 = (float*)((char*)d_ws + 524288);              // 64 KB proj1
    float* wsS1 = (float*)((char*)d_ws + 589824);              // 512 KB partial

    hipLaunchKernelGGL(prep_kernel, dim3(96), dim3(512), 0, stream,
                       dh, Wat, batt, wsB, wsP1);
    hipLaunchKernelGGL(fused_kernel, dim3(4096), dim3(256), 0, stream,
                       enc, wsB, wsP1, vvec, out, wsS1);
    hipLaunchKernelGGL(softmax_kernel, dim3(32), dim3(256), 0, stream, out, wsS1);
}